// Round 5
// baseline (284.427 us; speedup 1.0000x reference)
//
#include <hip/hip_runtime.h>

// TriAttention factorized implementation — all-f32 I/O (reference dtype),
// bf16 MFMA for the trilinear logits.
// dims: B=16, N(v,q,a)=96, D=256, H=128, G=2
// p = softmax over (v,q,a) of trilinear logits; all three contractions
// factor through the pairwise marginals of p (p never materialized):
//   c_v = (E_vq@qp + E_va@ap)/Z ; c_q = (E_vq^T@vp + E_qa@ap)/Z ;
//   c_a = (E_va^T@vp + E_qa^T@qp)/Z
// c is written f32 directly into d_out at its final column position and
// k_update rewrites d_out in place (each WG owns its token rows).
// Workspace ~6.8 MB.

#define B_  16
#define N_  96
#define D_  256
#define H_  128
#define CV  6     // v rows per k_logits workgroup
#define PAD 136   // LDS row stride in bf16 elems

typedef short bf16x8_t __attribute__((ext_vector_type(8)));
typedef float f32x4_t  __attribute__((ext_vector_type(4)));

__device__ __forceinline__ float bf2f(unsigned short u) {
    union { unsigned u32; float f; } x;
    x.u32 = ((unsigned)u) << 16;
    return x.f;
}
__device__ __forceinline__ unsigned short f2bf(float f) {
    union { float f; unsigned u; } x;
    x.f = f;
    unsigned r = x.u + 0x7fffu + ((x.u >> 16) & 1u);   // RNE
    return (unsigned short)(r >> 16);
}

// ---------------------------------------------------------------------------
// Kernel 1: six projections x@W+b -> [B,96,128]; tucker (p<3) relu'd + bf16
// for MFMA, value projections (p>=3) f32. grid = 6*16*3 = 288.
// ---------------------------------------------------------------------------
__global__ __launch_bounds__(256) void k_proj(
    const float* __restrict__ v, const float* __restrict__ q,
    const float* __restrict__ a,
    const float* __restrict__ Wvt, const float* __restrict__ bvt,
    const float* __restrict__ Wqt, const float* __restrict__ bqt,
    const float* __restrict__ Wat, const float* __restrict__ bat,
    const float* __restrict__ Wvp, const float* __restrict__ bvp,
    const float* __restrict__ Wqp, const float* __restrict__ bqp,
    const float* __restrict__ Wap, const float* __restrict__ bap,
    unsigned short* __restrict__ vt_o, unsigned short* __restrict__ qt_o,
    unsigned short* __restrict__ at_o,
    float* __restrict__ vp_o, float* __restrict__ qp_o, float* __restrict__ ap_o)
{
    int wg = blockIdx.x;
    int tc = wg % 3, b = (wg / 3) & 15, p = wg / 48;
    const float* xs_[6] = {v, q, a, v, q, a};
    const float* Ws_[6] = {Wvt, Wqt, Wat, Wvp, Wqp, Wap};
    const float* bs_[6] = {bvt, bqt, bat, bvp, bqp, bap};

    __shared__ __align__(16) float xls[32 * D_];   // 32 KB
    __shared__ __align__(16) float Wt[64 * H_];    // 32 KB per k-tile

    int tid = threadIdx.x;
    const float* x = xs_[p] + (size_t)(b * N_ + tc * 32) * D_;
    for (int i = tid; i < 2048; i += 256)          // 8192 floats as float4
        ((float4*)xls)[i] = ((const float4*)x)[i];

    int d = tid & 127, tg = tid >> 7;
    float bias = bs_[p][d];
    float acc[16];
#pragma unroll
    for (int i = 0; i < 16; i++) acc[i] = bias;

    const float* W = Ws_[p];
    for (int kt = 0; kt < 4; kt++) {
        __syncthreads();                           // xls ready / Wt free
        for (int i = tid; i < 2048; i += 256)
            ((float4*)Wt)[i] = ((const float4*)(W + kt * 64 * H_))[i];
        __syncthreads();
        for (int kb = 0; kb < 16; kb++) {
            int k = kb * 4;
            float w0 = Wt[(k + 0) * H_ + d];
            float w1 = Wt[(k + 1) * H_ + d];
            float w2 = Wt[(k + 2) * H_ + d];
            float w3 = Wt[(k + 3) * H_ + d];
            int kg = kt * 64 + k;
#pragma unroll
            for (int i = 0; i < 16; i++) {
                const float4 x4 = *(const float4*)&xls[(tg * 16 + i) * D_ + kg];
                acc[i] += x4.x * w0 + x4.y * w1 + x4.z * w2 + x4.w * w3;
            }
        }
    }

    int trow = b * N_ + tc * 32 + tg * 16;
    if (p < 3) {
        unsigned short* outs[3] = {vt_o, qt_o, at_o};
        unsigned short* o = outs[p];
#pragma unroll
        for (int i = 0; i < 16; i++)
            o[(trow + i) * H_ + d] = f2bf(fmaxf(acc[i], 0.f));   // FCNet relu
    } else {
        float* outs[3] = {vp_o, qp_o, ap_o};
        float* o = outs[p - 3];
#pragma unroll
        for (int i = 0; i < 16; i++) o[(trow + i) * H_ + d] = acc[i];
    }
}

// ---------------------------------------------------------------------------
// Kernel 2: logits + exp + marginals. WG = (b, v-chunk of CV=6), grid 256.
// S[q,a] = sum_h (qt[q,h]*vt[v,h]*Wg[h,g]) * at[a,h] via MFMA 16x16x32 bf16.
// E_vq (sum over a) / E_va (sum over q) via shuffles + LDS atomics; E_qa
// (sum over v) in registers, atomicAdd'ed into memset-zeroed global.
// Max-subtraction skipped: logits are O(1e-2); exp clamped (free) anyway.
// ---------------------------------------------------------------------------
__global__ __launch_bounds__(256) void k_logits(
    const unsigned short* __restrict__ vt, const unsigned short* __restrict__ qt,
    const unsigned short* __restrict__ at, const float* __restrict__ Wg,
    float* __restrict__ E_vq, float* __restrict__ E_va, float* __restrict__ E_qa)
{
    int b  = blockIdx.x & 15;
    int vc = blockIdx.x >> 4;
    int tid = threadIdx.x;

    __shared__ __align__(16) unsigned short at_l[N_ * PAD];
    __shared__ __align__(16) unsigned short qs_l[N_ * PAD];
    __shared__ __align__(16) float wv[2 * H_];
    __shared__ float evq_l[N_];
    __shared__ float eva_l[N_];

    const unsigned short* qtb = qt + (size_t)b * N_ * H_;
    const unsigned short* atb = at + (size_t)b * N_ * H_;
    for (int i = tid; i < 3072; i += 256) {
        int e = i * 4, t = e >> 7, h = e & 127;
        *(ushort4*)&at_l[t * PAD + h] = *(const ushort4*)&atb[e];
    }

    int wave = tid >> 6, lane = tid & 63, quad = lane >> 4, l15 = lane & 15;
    float eqa[2][9][4];
#pragma unroll
    for (int g = 0; g < 2; g++)
#pragma unroll
        for (int t2 = 0; t2 < 9; t2++)
#pragma unroll
            for (int r = 0; r < 4; r++) eqa[g][t2][r] = 0.f;

    for (int vl = 0; vl < CV; vl++) {
        int vrow = vc * CV + vl;
        {   // w_g[h] = vt[v,h] * Wg[h,g]
            int h = tid & 127, g2 = tid >> 7;
            wv[g2 * H_ + h] = bf2f(vt[(b * N_ + vrow) * H_ + h]) * Wg[h * 2 + g2];
        }
        __syncthreads();

        for (int g = 0; g < 2; g++) {
            if (tid < 96) evq_l[tid] = 0.f;
            else if (tid >= 128 && tid < 224) eva_l[tid - 128] = 0.f;
            // scaled A operand: qs[q,h] = bf16(qt[q,h] * wv[g][h])
            for (int it = 0; it < 12; it++) {
                int i = tid + it * 256;
                int e = i * 4, t = e >> 7, h = e & 127;
                ushort4 qv = *(const ushort4*)&qtb[e];
                float4  wf = *(const float4*)&wv[g * H_ + h];
                ushort4 o;
                o.x = f2bf(bf2f(qv.x) * wf.x);
                o.y = f2bf(bf2f(qv.y) * wf.y);
                o.z = f2bf(bf2f(qv.z) * wf.z);
                o.w = f2bf(bf2f(qv.w) * wf.w);
                *(ushort4*)&qs_l[t * PAD + h] = o;
            }
            __syncthreads();

#pragma unroll
            for (int ti = 0; ti < 9; ti++) {
                int tile = wave * 9 + ti;
                int qi = tile / 6, aj = tile - qi * 6;
                f32x4_t acc = {0.f, 0.f, 0.f, 0.f};
#pragma unroll
                for (int ks = 0; ks < 4; ks++) {
                    bf16x8_t afr = *(const bf16x8_t*)&qs_l[(qi * 16 + l15) * PAD + ks * 32 + quad * 8];
                    bf16x8_t bfr = *(const bf16x8_t*)&at_l[(aj * 16 + l15) * PAD + ks * 32 + quad * 8];
                    acc = __builtin_amdgcn_mfma_f32_16x16x32_bf16(afr, bfr, acc, 0, 0, 0);
                }
                // C/D: col(a)=lane&15, row(q)=quad*4+reg  [m89-verified]
                float e0 = __expf(fminf(fmaxf(acc[0], -30.f), 30.f));
                float e1 = __expf(fminf(fmaxf(acc[1], -30.f), 30.f));
                float e2 = __expf(fminf(fmaxf(acc[2], -30.f), 30.f));
                float e3 = __expf(fminf(fmaxf(acc[3], -30.f), 30.f));
                eqa[g][ti][0] += e0; eqa[g][ti][1] += e1;
                eqa[g][ti][2] += e2; eqa[g][ti][3] += e3;
                // E_vq: sum over a (cols, l15 dim) per q row
                float s0 = e0, s1 = e1, s2 = e2, s3 = e3;
#pragma unroll
                for (int m = 1; m < 16; m <<= 1) {
                    s0 += __shfl_xor(s0, m); s1 += __shfl_xor(s1, m);
                    s2 += __shfl_xor(s2, m); s3 += __shfl_xor(s3, m);
                }
                if (l15 == 0) {
                    int qr = qi * 16 + quad * 4;
                    atomicAdd(&evq_l[qr + 0], s0);
                    atomicAdd(&evq_l[qr + 1], s1);
                    atomicAdd(&evq_l[qr + 2], s2);
                    atomicAdd(&evq_l[qr + 3], s3);
                }
                // E_va: sum over q rows (4 local + across quads)
                float csum = e0 + e1 + e2 + e3;
                csum += __shfl_xor(csum, 16);
                csum += __shfl_xor(csum, 32);
                if (lane < 16) atomicAdd(&eva_l[aj * 16 + lane], csum);
            }
            __syncthreads();
            int base = ((b * 2 + g) * N_ + vrow) * N_;
            if (tid < 96) E_vq[base + tid] = evq_l[tid];
            else if (tid >= 128 && tid < 224) E_va[base + tid - 128] = eva_l[tid - 128];
            __syncthreads();
        }
    }

    // E_qa accumulation (global pre-zeroed; 16 WGs contend per cell)
#pragma unroll
    for (int g = 0; g < 2; g++)
#pragma unroll
        for (int ti = 0; ti < 9; ti++) {
            int tile = wave * 9 + ti, qi = tile / 6, aj = tile - qi * 6;
#pragma unroll
            for (int r = 0; r < 4; r++) {
                int qq = qi * 16 + quad * 4 + r, aa = aj * 16 + l15;
                atomicAdd(&E_qa[(b * 2 + g) * 9216 + qq * 96 + aa], eqa[g][ti][r]);
            }
        }
}

// ---------------------------------------------------------------------------
// Kernel 3: Z = sum(E_vq) per (b,g); Zinv = 1/Z. grid = 32.
// ---------------------------------------------------------------------------
__global__ __launch_bounds__(256) void k_zsum(
    const float* __restrict__ E_vq, float* __restrict__ Zinv)
{
    int b = blockIdx.x >> 1, g = blockIdx.x & 1;
    int tid = threadIdx.x;
    float z = 0.f;
    const float* ev = E_vq + (b * 2 + g) * 9216;
    for (int i = tid; i < 9216; i += 256) z += ev[i];
    __shared__ float red[256];
    red[tid] = z;
    __syncthreads();
    for (int s = 128; s > 0; s >>= 1) {
        if (tid < s) red[tid] += red[tid + s];
        __syncthreads();
    }
    if (tid == 0) Zinv[b * 2 + g] = 1.f / fmaxf(red[0], 1e-30f);
}

// ---------------------------------------------------------------------------
// Kernel 4: attended contexts from marginals; c written f32 directly into
// d_out at final positions (c_v/c_q col=g*128+d, c_a col=d*2+g, matching the
// reference's permute+reshape). grid = 3*16*2*6 = 576.
// ---------------------------------------------------------------------------
__global__ __launch_bounds__(256) void k_ctx(
    const float* __restrict__ E_vq, const float* __restrict__ E_va,
    const float* __restrict__ E_qa,
    const float* __restrict__ vp, const float* __restrict__ qp,
    const float* __restrict__ ap, const float* __restrict__ Zinv,
    float* __restrict__ out)
{
    int wg = blockIdx.x;
    int tc = wg % 6, g = (wg / 6) & 1, b = (wg / 12) & 15, o = wg / 192;
    int tid = threadIdx.x;
    __shared__ __align__(16) float E1l[16 * 100];
    __shared__ __align__(16) float E2l[16 * 100];
    int t0 = tc * 16;
    const float* Evq = E_vq + (b * 2 + g) * 9216;
    const float* Eva = E_va + (b * 2 + g) * 9216;
    const float* Eqa = E_qa + (b * 2 + g) * 9216;

    if (o == 0) {          // c_v: E1[t=v][j=q]=E_vq, E2[t=v][j=a]=E_va
        for (int i = tid; i < 1536; i += 256) {
            int t = i / 96, j = i - t * 96;
            E1l[t * 100 + j] = Evq[(t0 + t) * 96 + j];
            E2l[t * 100 + j] = Eva[(t0 + t) * 96 + j];
        }
    } else if (o == 1) {   // c_q: E1[t=q][j=v]=E_vq^T, E2[t=q][j=a]=E_qa
        for (int i = tid; i < 1536; i += 256) {
            int t = i & 15, j = i >> 4;
            E1l[t * 100 + j] = Evq[j * 96 + t0 + t];
        }
        for (int i = tid; i < 1536; i += 256) {
            int t = i / 96, j = i - t * 96;
            E2l[t * 100 + j] = Eqa[(t0 + t) * 96 + j];
        }
    } else {               // c_a: E1[t=a][j=v]=E_va^T, E2[t=a][j=q]=E_qa^T
        for (int i = tid; i < 1536; i += 256) {
            int t = i & 15, j = i >> 4;
            E1l[t * 100 + j] = Eva[j * 96 + t0 + t];
            E2l[t * 100 + j] = Eqa[j * 96 + t0 + t];
        }
    }
    __syncthreads();

    const float* P1 = ((o == 0) ? qp : vp) + b * N_ * H_;
    const float* P2 = ((o == 2) ? qp : ap) + b * N_ * H_;
    int d = tid & 127, tg = tid >> 7;
    float acc[8] = {0.f, 0.f, 0.f, 0.f, 0.f, 0.f, 0.f, 0.f};
    for (int jb = 0; jb < 24; jb++) {
        int j4 = jb * 4;
        float p10 = P1[(j4 + 0) * H_ + d], p11 = P1[(j4 + 1) * H_ + d];
        float p12 = P1[(j4 + 2) * H_ + d], p13 = P1[(j4 + 3) * H_ + d];
        float p20 = P2[(j4 + 0) * H_ + d], p21 = P2[(j4 + 1) * H_ + d];
        float p22 = P2[(j4 + 2) * H_ + d], p23 = P2[(j4 + 3) * H_ + d];
#pragma unroll
        for (int t8 = 0; t8 < 8; t8++) {
            int t = tg * 8 + t8;
            float4 e1 = *(const float4*)&E1l[t * 100 + j4];
            float4 e2 = *(const float4*)&E2l[t * 100 + j4];
            acc[t8] += e1.x * p10 + e1.y * p11 + e1.z * p12 + e1.w * p13
                     + e2.x * p20 + e2.y * p21 + e2.z * p22 + e2.w * p23;
        }
    }
    float zi = Zinv[b * 2 + g];
    float* ob = out + (size_t)((o * B_ + b) * N_) * 256;
#pragma unroll
    for (int t8 = 0; t8 < 8; t8++) {
        int T = t0 + tg * 8 + t8;
        int col = (o == 2) ? (d * 2 + g) : (g * 128 + d);
        ob[T * 256 + col] = acc[t8] * zi;
    }
}

// ---------------------------------------------------------------------------
// Kernel 5: updated_x = x + c_x @ Wxu + bxu, in place over d_out (c_x was
// stored there by k_ctx). grid = 3*16*12 = 576; each WG owns 8 token rows.
// ---------------------------------------------------------------------------
__global__ __launch_bounds__(256) void k_update(
    const float* __restrict__ v, const float* __restrict__ q,
    const float* __restrict__ a,
    const float* __restrict__ Wvu, const float* __restrict__ bvu,
    const float* __restrict__ Wqu, const float* __restrict__ bqu,
    const float* __restrict__ Wau, const float* __restrict__ bau,
    float* __restrict__ out)
{
    int wg = blockIdx.x;
    int tc = wg % 12, b = (wg / 12) & 15, o = wg / 192;
    int tid = threadIdx.x;   // output column n in [0,256)
    const float* xs_[3] = {v, q, a};
    const float* Ws_[3] = {Wvu, Wqu, Wau};
    const float* bs_[3] = {bvu, bqu, bau};
    int t0 = tc * 8;

    __shared__ __align__(16) float c_l[8 * 256];   // 8 KB
    float* cbase = out + (size_t)((o * B_ + b) * N_ + t0) * 256;
    for (int i = tid; i < 2048; i += 256) c_l[i] = cbase[i];
    __syncthreads();   // all reads of cbase complete before any write below

    const float* W = Ws_[o];
    const float* x = xs_[o] + (size_t)(b * N_ + t0) * 256;
    float bias = bs_[o][tid];
    float acc[8];
#pragma unroll
    for (int t = 0; t < 8; t++) acc[t] = bias + x[t * 256 + tid];

    for (int kb = 0; kb < 64; kb++) {
        int k = kb * 4;
        float w0 = W[(k + 0) * 256 + tid];
        float w1 = W[(k + 1) * 256 + tid];
        float w2 = W[(k + 2) * 256 + tid];
        float w3 = W[(k + 3) * 256 + tid];
#pragma unroll
        for (int t = 0; t < 8; t++) {
            float4 c4 = *(const float4*)&c_l[t * 256 + k];
            acc[t] += c4.x * w0 + c4.y * w1 + c4.z * w2 + c4.w * w3;
        }
    }
#pragma unroll
    for (int t = 0; t < 8; t++) cbase[t * 256 + tid] = acc[t];
}

// ---------------------------------------------------------------------------
extern "C" void kernel_launch(void* const* d_in, const int* in_sizes, int n_in,
                              void* d_out, int out_size, void* d_ws, size_t ws_size,
                              hipStream_t stream)
{
    const float* v   = (const float*)d_in[0];
    const float* q   = (const float*)d_in[1];
    const float* a   = (const float*)d_in[2];
    const float* Wvt = (const float*)d_in[3];
    const float* bvt = (const float*)d_in[4];
    const float* Wqt = (const float*)d_in[5];
    const float* bqt = (const float*)d_in[6];
    const float* Wat = (const float*)d_in[7];
    const float* bat = (const float*)d_in[8];
    const float* Wg  = (const float*)d_in[9];
    const float* Wvp = (const float*)d_in[10];
    const float* bvp = (const float*)d_in[11];
    const float* Wqp = (const float*)d_in[12];
    const float* bqp = (const float*)d_in[13];
    const float* Wap = (const float*)d_in[14];
    const float* bap = (const float*)d_in[15];
    const float* Wvu = (const float*)d_in[16];
    const float* bvu = (const float*)d_in[17];
    const float* Wqu = (const float*)d_in[18];
    const float* bqu = (const float*)d_in[19];
    const float* Wau = (const float*)d_in[20];
    const float* bau = (const float*)d_in[21];

    char* ws = (char*)d_ws;
    size_t off = 0;
    auto alloc = [&](size_t bytes) {
        char* p = ws + off;
        off += (bytes + 255) & ~(size_t)255;
        return (void*)p;
    };
    unsigned short* vt = (unsigned short*)alloc((size_t)B_ * N_ * H_ * 2);
    unsigned short* qt = (unsigned short*)alloc((size_t)B_ * N_ * H_ * 2);
    unsigned short* at = (unsigned short*)alloc((size_t)B_ * N_ * H_ * 2);
    float* vpb  = (float*)alloc((size_t)B_ * N_ * H_ * 4);
    float* qpb  = (float*)alloc((size_t)B_ * N_ * H_ * 4);
    float* apb  = (float*)alloc((size_t)B_ * N_ * H_ * 4);
    float* E_vq = (float*)alloc((size_t)B_ * 2 * 9216 * 4);
    float* E_va = (float*)alloc((size_t)B_ * 2 * 9216 * 4);
    float* E_qa = (float*)alloc((size_t)B_ * 2 * 9216 * 4);
    float* Zinv = (float*)alloc(256);
    // total ~6.8 MB

    hipMemsetAsync(E_qa, 0, (size_t)B_ * 2 * 9216 * 4, stream);
    k_proj<<<288, 256, 0, stream>>>(v, q, a, Wvt, bvt, Wqt, bqt, Wat, bat,
                                    Wvp, bvp, Wqp, bqp, Wap, bap,
                                    vt, qt, at, vpb, qpb, apb);
    k_logits<<<256, 256, 0, stream>>>(vt, qt, at, Wg, E_vq, E_va, E_qa);
    k_zsum<<<32, 256, 0, stream>>>(E_vq, Zinv);
    k_ctx<<<576, 256, 0, stream>>>(E_vq, E_va, E_qa, vpb, qpb, apb, Zinv,
                                   (float*)d_out);
    k_update<<<576, 256, 0, stream>>>(v, q, a, Wvu, bvu, Wqu, bqu, Wau, bau,
                                      (float*)d_out);
}

// Round 6
// 224.353 us; speedup vs baseline: 1.2678x; 1.2678x over previous
//
#include <hip/hip_runtime.h>

// TriAttention factorized implementation — all-f32 I/O, bf16 MFMA logits.
// dims: B=16, N(v,q,a)=96, D=256, H=128, G=2
// l[v,q,a,g] = sum_h (qt[q,h]*Wg[h,g]) * (at[a,h]*vt[v,h]); contractions
// factor through pairwise marginals of softmax(l) (p never materialized).
// k_logits R5 restructure: WG=(b,vc,g) grid 512 (2 WG/CU co-resident),
// qg staged once/WG, at*vt[v] staged per v, 3x3 tile blocks per wave.

#define B_  16
#define N_  96
#define D_  256
#define H_  128
#define CV  6     // v rows per k_logits workgroup
#define PAD 136   // LDS row stride in bf16 elems (272 B, 16B-aligned)

typedef short bf16x8_t __attribute__((ext_vector_type(8)));
typedef float f32x4_t  __attribute__((ext_vector_type(4)));

__device__ __forceinline__ float bf2f(unsigned short u) {
    union { unsigned u32; float f; } x;
    x.u32 = ((unsigned)u) << 16;
    return x.f;
}
__device__ __forceinline__ unsigned short f2bf(float f) {
    union { float f; unsigned u; } x;
    x.f = f;
    unsigned r = x.u + 0x7fffu + ((x.u >> 16) & 1u);   // RNE
    return (unsigned short)(r >> 16);
}

// ---------------------------------------------------------------------------
// Kernel 1: six projections x@W+b -> [B,96,128]; tucker (p<3) relu'd + bf16
// for MFMA, value projections (p>=3) f32. grid = 6*16*3 = 288.
// ---------------------------------------------------------------------------
__global__ __launch_bounds__(256) void k_proj(
    const float* __restrict__ v, const float* __restrict__ q,
    const float* __restrict__ a,
    const float* __restrict__ Wvt, const float* __restrict__ bvt,
    const float* __restrict__ Wqt, const float* __restrict__ bqt,
    const float* __restrict__ Wat, const float* __restrict__ bat,
    const float* __restrict__ Wvp, const float* __restrict__ bvp,
    const float* __restrict__ Wqp, const float* __restrict__ bqp,
    const float* __restrict__ Wap, const float* __restrict__ bap,
    unsigned short* __restrict__ vt_o, unsigned short* __restrict__ qt_o,
    unsigned short* __restrict__ at_o,
    float* __restrict__ vp_o, float* __restrict__ qp_o, float* __restrict__ ap_o)
{
    int wg = blockIdx.x;
    int tc = wg % 3, b = (wg / 3) & 15, p = wg / 48;
    const float* xs_[6] = {v, q, a, v, q, a};
    const float* Ws_[6] = {Wvt, Wqt, Wat, Wvp, Wqp, Wap};
    const float* bs_[6] = {bvt, bqt, bat, bvp, bqp, bap};

    __shared__ __align__(16) float xls[32 * D_];   // 32 KB
    __shared__ __align__(16) float Wt[64 * H_];    // 32 KB per k-tile

    int tid = threadIdx.x;
    const float* x = xs_[p] + (size_t)(b * N_ + tc * 32) * D_;
    for (int i = tid; i < 2048; i += 256)
        ((float4*)xls)[i] = ((const float4*)x)[i];

    int d = tid & 127, tg = tid >> 7;
    float bias = bs_[p][d];
    float acc[16];
#pragma unroll
    for (int i = 0; i < 16; i++) acc[i] = bias;

    const float* W = Ws_[p];
    for (int kt = 0; kt < 4; kt++) {
        __syncthreads();
        for (int i = tid; i < 2048; i += 256)
            ((float4*)Wt)[i] = ((const float4*)(W + kt * 64 * H_))[i];
        __syncthreads();
        for (int kb = 0; kb < 16; kb++) {
            int k = kb * 4;
            float w0 = Wt[(k + 0) * H_ + d];
            float w1 = Wt[(k + 1) * H_ + d];
            float w2 = Wt[(k + 2) * H_ + d];
            float w3 = Wt[(k + 3) * H_ + d];
            int kg = kt * 64 + k;
#pragma unroll
            for (int i = 0; i < 16; i++) {
                const float4 x4 = *(const float4*)&xls[(tg * 16 + i) * D_ + kg];
                acc[i] += x4.x * w0 + x4.y * w1 + x4.z * w2 + x4.w * w3;
            }
        }
    }

    int trow = b * N_ + tc * 32 + tg * 16;
    if (p < 3) {
        unsigned short* outs[3] = {vt_o, qt_o, at_o};
        unsigned short* o = outs[p];
#pragma unroll
        for (int i = 0; i < 16; i++)
            o[(trow + i) * H_ + d] = f2bf(fmaxf(acc[i], 0.f));   // FCNet relu
    } else {
        float* outs[3] = {vp_o, qp_o, ap_o};
        float* o = outs[p - 3];
#pragma unroll
        for (int i = 0; i < 16; i++) o[(trow + i) * H_ + d] = acc[i];
    }
}

// ---------------------------------------------------------------------------
// Kernel 2 (R5): logits + exp + marginals. WG = (b, vc of CV=6, g), grid 512
// -> 2 WGs/CU co-resident (LDS 53 KB). Per WG: stage qg = qt*Wg[:,g] once;
// per v: stage as = at*vt[v] (g-independent regrouping), then 36 tiles as
// 3x3 blocks per wave (frag reuse: 24 ds_read_b128/v vs 144 before).
// E_vq/E_va via shuffles + LDS atomics; E_qa registers -> global atomics.
// ---------------------------------------------------------------------------
__global__ __launch_bounds__(256) void k_logits(
    const unsigned short* __restrict__ vt, const unsigned short* __restrict__ qt,
    const unsigned short* __restrict__ at, const float* __restrict__ Wg,
    float* __restrict__ E_vq, float* __restrict__ E_va, float* __restrict__ E_qa)
{
    int bid = blockIdx.x;
    int b = bid >> 5, vc = (bid >> 1) & 15, g = bid & 1;
    int tid = threadIdx.x;

    __shared__ __align__(16) unsigned short qg_l[N_ * PAD];  // qt*Wg[:,g], 26112 B
    __shared__ __align__(16) unsigned short as_l[N_ * PAD];  // at*vt[v], per v
    __shared__ float evq_l[N_];
    __shared__ float eva_l[N_];

    const unsigned short* qtb = qt + (size_t)b * N_ * H_;
    const unsigned short* atb = at + (size_t)b * N_ * H_;
    const unsigned short* vtb = vt + (size_t)(b * N_ + vc * CV) * H_;

    // stage qg once (A operand, reused for all 6 v rows)
    for (int it = 0; it < 12; it++) {
        int i = tid + it * 256;
        int e = i * 4, t = e >> 7, h = e & 127;
        ushort4 qv = *(const ushort4*)&qtb[e];
        float w0 = Wg[(h + 0) * 2 + g], w1 = Wg[(h + 1) * 2 + g];
        float w2 = Wg[(h + 2) * 2 + g], w3 = Wg[(h + 3) * 2 + g];
        ushort4 o;
        o.x = f2bf(bf2f(qv.x) * w0);
        o.y = f2bf(bf2f(qv.y) * w1);
        o.z = f2bf(bf2f(qv.z) * w2);
        o.w = f2bf(bf2f(qv.w) * w3);
        *(ushort4*)&qg_l[t * PAD + h] = o;
    }
    if (tid < 96) evq_l[tid] = 0.f;
    else if (tid < 192) eva_l[tid - 96] = 0.f;

    int wave = tid >> 6, lane = tid & 63, quad = lane >> 4, l15 = lane & 15;
    int qi0 = (wave >> 1) * 3, aj0 = (wave & 1) * 3;   // 3x3 tile block of 6x6

    float eqa[3][3][4];
#pragma unroll
    for (int i = 0; i < 3; i++)
#pragma unroll
        for (int j = 0; j < 3; j++)
#pragma unroll
            for (int r = 0; r < 4; r++) eqa[i][j][r] = 0.f;

    for (int vl = 0; vl < CV; vl++) {
        __syncthreads();   // prev-v reads of as_l done; evq/eva zeroed
        // stage as = at * vt[v]  (B operand; vt row read from L2, broadcast)
        const unsigned short* vrow = vtb + vl * H_;
        for (int it = 0; it < 12; it++) {
            int i = tid + it * 256;
            int e = i * 4, t = e >> 7, h = e & 127;
            ushort4 av = *(const ushort4*)&atb[e];
            ushort4 vv = *(const ushort4*)&vrow[h];
            ushort4 o;
            o.x = f2bf(bf2f(av.x) * bf2f(vv.x));
            o.y = f2bf(bf2f(av.y) * bf2f(vv.y));
            o.z = f2bf(bf2f(av.z) * bf2f(vv.z));
            o.w = f2bf(bf2f(av.w) * bf2f(vv.w));
            *(ushort4*)&as_l[t * PAD + h] = o;
        }
        __syncthreads();

        // 3x3 MFMA block with fragment reuse
        f32x4_t acc[3][3];
#pragma unroll
        for (int i = 0; i < 3; i++)
#pragma unroll
            for (int j = 0; j < 3; j++)
                acc[i][j] = (f32x4_t){0.f, 0.f, 0.f, 0.f};
#pragma unroll
        for (int ks = 0; ks < 4; ks++) {
            bf16x8_t af[3], bfr[3];
#pragma unroll
            for (int i = 0; i < 3; i++)
                af[i] = *(const bf16x8_t*)&qg_l[((qi0 + i) * 16 + l15) * PAD + ks * 32 + quad * 8];
#pragma unroll
            for (int j = 0; j < 3; j++)
                bfr[j] = *(const bf16x8_t*)&as_l[((aj0 + j) * 16 + l15) * PAD + ks * 32 + quad * 8];
#pragma unroll
            for (int i = 0; i < 3; i++)
#pragma unroll
                for (int j = 0; j < 3; j++)
                    acc[i][j] = __builtin_amdgcn_mfma_f32_16x16x32_bf16(af[i], bfr[j], acc[i][j], 0, 0, 0);
        }

        // exp + on-the-fly row/col partials
        // C/D: col(a)=l15, row(q)=quad*4+r  [m89-verified]
        float s[3][4];     // per-i row sums over j (still per-l15 lane)
        float c[3];        // per-j col sums over i,r (still per-quad)
#pragma unroll
        for (int i = 0; i < 3; i++) {
            s[i][0] = 0.f; s[i][1] = 0.f; s[i][2] = 0.f; s[i][3] = 0.f;
        }
        c[0] = 0.f; c[1] = 0.f; c[2] = 0.f;
#pragma unroll
        for (int i = 0; i < 3; i++)
#pragma unroll
            for (int j = 0; j < 3; j++) {
                float e0 = __expf(fminf(fmaxf(acc[i][j][0], -30.f), 30.f));
                float e1 = __expf(fminf(fmaxf(acc[i][j][1], -30.f), 30.f));
                float e2 = __expf(fminf(fmaxf(acc[i][j][2], -30.f), 30.f));
                float e3 = __expf(fminf(fmaxf(acc[i][j][3], -30.f), 30.f));
                eqa[i][j][0] += e0; eqa[i][j][1] += e1;
                eqa[i][j][2] += e2; eqa[i][j][3] += e3;
                s[i][0] += e0; s[i][1] += e1; s[i][2] += e2; s[i][3] += e3;
                c[j] += e0 + e1 + e2 + e3;
            }
        // E_vq rows: reduce s over l15 (xor 1,2,4,8 stays in 16-group)
#pragma unroll
        for (int i = 0; i < 3; i++) {
            float s0 = s[i][0], s1 = s[i][1], s2 = s[i][2], s3 = s[i][3];
#pragma unroll
            for (int m = 1; m < 16; m <<= 1) {
                s0 += __shfl_xor(s0, m); s1 += __shfl_xor(s1, m);
                s2 += __shfl_xor(s2, m); s3 += __shfl_xor(s3, m);
            }
            if (l15 == 0) {
                int qr = (qi0 + i) * 16 + quad * 4;
                atomicAdd(&evq_l[qr + 0], s0);
                atomicAdd(&evq_l[qr + 1], s1);
                atomicAdd(&evq_l[qr + 2], s2);
                atomicAdd(&evq_l[qr + 3], s3);
            }
        }
        // E_va cols: reduce c over quads (xor 16, 32)
#pragma unroll
        for (int j = 0; j < 3; j++) {
            float cs = c[j];
            cs += __shfl_xor(cs, 16);
            cs += __shfl_xor(cs, 32);
            if (lane < 16) atomicAdd(&eva_l[(aj0 + j) * 16 + l15], cs);
        }
        __syncthreads();
        int base = ((b * 2 + g) * N_ + vc * CV + vl) * N_;
        if (tid < 96)       { E_vq[base + tid] = evq_l[tid];       evq_l[tid] = 0.f; }
        else if (tid < 192) { E_va[base + tid - 96] = eva_l[tid - 96]; eva_l[tid - 96] = 0.f; }
    }

    // E_qa flush (global pre-zeroed; 16 vc-WGs contend per cell)
    float* Eq = E_qa + (size_t)(b * 2 + g) * 9216;
#pragma unroll
    for (int i = 0; i < 3; i++)
#pragma unroll
        for (int j = 0; j < 3; j++)
#pragma unroll
            for (int r = 0; r < 4; r++) {
                int qq = (qi0 + i) * 16 + quad * 4 + r;
                int aa = (aj0 + j) * 16 + l15;
                atomicAdd(&Eq[qq * 96 + aa], eqa[i][j][r]);
            }
}

// ---------------------------------------------------------------------------
// Kernel 3: Z = sum(E_vq) per (b,g); Zinv = 1/Z. grid = 32.
// ---------------------------------------------------------------------------
__global__ __launch_bounds__(256) void k_zsum(
    const float* __restrict__ E_vq, float* __restrict__ Zinv)
{
    int b = blockIdx.x >> 1, g = blockIdx.x & 1;
    int tid = threadIdx.x;
    float z = 0.f;
    const float* ev = E_vq + (b * 2 + g) * 9216;
    for (int i = tid; i < 9216; i += 256) z += ev[i];
    __shared__ float red[256];
    red[tid] = z;
    __syncthreads();
    for (int s = 128; s > 0; s >>= 1) {
        if (tid < s) red[tid] += red[tid + s];
        __syncthreads();
    }
    if (tid == 0) Zinv[b * 2 + g] = 1.f / fmaxf(red[0], 1e-30f);
}

// ---------------------------------------------------------------------------
// Kernel 4: attended contexts from marginals; c written f32 directly into
// d_out at final positions (c_v/c_q col=g*128+d, c_a col=d*2+g). grid = 576.
// ---------------------------------------------------------------------------
__global__ __launch_bounds__(256) void k_ctx(
    const float* __restrict__ E_vq, const float* __restrict__ E_va,
    const float* __restrict__ E_qa,
    const float* __restrict__ vp, const float* __restrict__ qp,
    const float* __restrict__ ap, const float* __restrict__ Zinv,
    float* __restrict__ out)
{
    int wg = blockIdx.x;
    int tc = wg % 6, g = (wg / 6) & 1, b = (wg / 12) & 15, o = wg / 192;
    int tid = threadIdx.x;
    __shared__ __align__(16) float E1l[16 * 100];
    __shared__ __align__(16) float E2l[16 * 100];
    int t0 = tc * 16;
    const float* Evq = E_vq + (b * 2 + g) * 9216;
    const float* Eva = E_va + (b * 2 + g) * 9216;
    const float* Eqa = E_qa + (b * 2 + g) * 9216;

    if (o == 0) {          // c_v: E1[t=v][j=q]=E_vq, E2[t=v][j=a]=E_va
        for (int i = tid; i < 1536; i += 256) {
            int t = i / 96, j = i - t * 96;
            E1l[t * 100 + j] = Evq[(t0 + t) * 96 + j];
            E2l[t * 100 + j] = Eva[(t0 + t) * 96 + j];
        }
    } else if (o == 1) {   // c_q: E1[t=q][j=v]=E_vq^T, E2[t=q][j=a]=E_qa
        for (int i = tid; i < 1536; i += 256) {
            int t = i & 15, j = i >> 4;
            E1l[t * 100 + j] = Evq[j * 96 + t0 + t];
        }
        for (int i = tid; i < 1536; i += 256) {
            int t = i / 96, j = i - t * 96;
            E2l[t * 100 + j] = Eqa[(t0 + t) * 96 + j];
        }
    } else {               // c_a: E1[t=a][j=v]=E_va^T, E2[t=a][j=q]=E_qa^T
        for (int i = tid; i < 1536; i += 256) {
            int t = i & 15, j = i >> 4;
            E1l[t * 100 + j] = Eva[j * 96 + t0 + t];
            E2l[t * 100 + j] = Eqa[j * 96 + t0 + t];
        }
    }
    __syncthreads();

    const float* P1 = ((o == 0) ? qp : vp) + b * N_ * H_;
    const float* P2 = ((o == 2) ? qp : ap) + b * N_ * H_;
    int d = tid & 127, tg = tid >> 7;
    float acc[8] = {0.f, 0.f, 0.f, 0.f, 0.f, 0.f, 0.f, 0.f};
    for (int jb = 0; jb < 24; jb++) {
        int j4 = jb * 4;
        float p10 = P1[(j4 + 0) * H_ + d], p11 = P1[(j4 + 1) * H_ + d];
        float p12 = P1[(j4 + 2) * H_ + d], p13 = P1[(j4 + 3) * H_ + d];
        float p20 = P2[(j4 + 0) * H_ + d], p21 = P2[(j4 + 1) * H_ + d];
        float p22 = P2[(j4 + 2) * H_ + d], p23 = P2[(j4 + 3) * H_ + d];
#pragma unroll
        for (int t8 = 0; t8 < 8; t8++) {
            int t = tg * 8 + t8;
            float4 e1 = *(const float4*)&E1l[t * 100 + j4];
            float4 e2 = *(const float4*)&E2l[t * 100 + j4];
            acc[t8] += e1.x * p10 + e1.y * p11 + e1.z * p12 + e1.w * p13
                     + e2.x * p20 + e2.y * p21 + e2.z * p22 + e2.w * p23;
        }
    }
    float zi = Zinv[b * 2 + g];
    float* ob = out + (size_t)((o * B_ + b) * N_) * 256;
#pragma unroll
    for (int t8 = 0; t8 < 8; t8++) {
        int T = t0 + tg * 8 + t8;
        int col = (o == 2) ? (d * 2 + g) : (g * 128 + d);
        ob[T * 256 + col] = acc[t8] * zi;
    }
}

// ---------------------------------------------------------------------------
// Kernel 5: updated_x = x + c_x @ Wxu + bxu, in place over d_out. grid = 576.
// ---------------------------------------------------------------------------
__global__ __launch_bounds__(256) void k_update(
    const float* __restrict__ v, const float* __restrict__ q,
    const float* __restrict__ a,
    const float* __restrict__ Wvu, const float* __restrict__ bvu,
    const float* __restrict__ Wqu, const float* __restrict__ bqu,
    const float* __restrict__ Wau, const float* __restrict__ bau,
    float* __restrict__ out)
{
    int wg = blockIdx.x;
    int tc = wg % 12, b = (wg / 12) & 15, o = wg / 192;
    int tid = threadIdx.x;
    const float* xs_[3] = {v, q, a};
    const float* Ws_[3] = {Wvu, Wqu, Wau};
    const float* bs_[3] = {bvu, bqu, bau};
    int t0 = tc * 8;

    __shared__ __align__(16) float c_l[8 * 256];
    float* cbase = out + (size_t)((o * B_ + b) * N_ + t0) * 256;
    for (int i = tid; i < 2048; i += 256) c_l[i] = cbase[i];
    __syncthreads();

    const float* W = Ws_[o];
    const float* x = xs_[o] + (size_t)(b * N_ + t0) * 256;
    float bias = bs_[o][tid];
    float acc[8];
#pragma unroll
    for (int t = 0; t < 8; t++) acc[t] = bias + x[t * 256 + tid];

    for (int kb = 0; kb < 64; kb++) {
        int k = kb * 4;
        float w0 = W[(k + 0) * 256 + tid];
        float w1 = W[(k + 1) * 256 + tid];
        float w2 = W[(k + 2) * 256 + tid];
        float w3 = W[(k + 3) * 256 + tid];
#pragma unroll
        for (int t = 0; t < 8; t++) {
            float4 c4 = *(const float4*)&c_l[t * 256 + k];
            acc[t] += c4.x * w0 + c4.y * w1 + c4.z * w2 + c4.w * w3;
        }
    }
#pragma unroll
    for (int t = 0; t < 8; t++) cbase[t * 256 + tid] = acc[t];
}

// ---------------------------------------------------------------------------
extern "C" void kernel_launch(void* const* d_in, const int* in_sizes, int n_in,
                              void* d_out, int out_size, void* d_ws, size_t ws_size,
                              hipStream_t stream)
{
    const float* v   = (const float*)d_in[0];
    const float* q   = (const float*)d_in[1];
    const float* a   = (const float*)d_in[2];
    const float* Wvt = (const float*)d_in[3];
    const float* bvt = (const float*)d_in[4];
    const float* Wqt = (const float*)d_in[5];
    const float* bqt = (const float*)d_in[6];
    const float* Wat = (const float*)d_in[7];
    const float* bat = (const float*)d_in[8];
    const float* Wg  = (const float*)d_in[9];
    const float* Wvp = (const float*)d_in[10];
    const float* bvp = (const float*)d_in[11];
    const float* Wqp = (const float*)d_in[12];
    const float* bqp = (const float*)d_in[13];
    const float* Wap = (const float*)d_in[14];
    const float* bap = (const float*)d_in[15];
    const float* Wvu = (const float*)d_in[16];
    const float* bvu = (const float*)d_in[17];
    const float* Wqu = (const float*)d_in[18];
    const float* bqu = (const float*)d_in[19];
    const float* Wau = (const float*)d_in[20];
    const float* bau = (const float*)d_in[21];

    char* ws = (char*)d_ws;
    size_t off = 0;
    auto alloc = [&](size_t bytes) {
        char* p = ws + off;
        off += (bytes + 255) & ~(size_t)255;
        return (void*)p;
    };
    unsigned short* vt = (unsigned short*)alloc((size_t)B_ * N_ * H_ * 2);
    unsigned short* qt = (unsigned short*)alloc((size_t)B_ * N_ * H_ * 2);
    unsigned short* at = (unsigned short*)alloc((size_t)B_ * N_ * H_ * 2);
    float* vpb  = (float*)alloc((size_t)B_ * N_ * H_ * 4);
    float* qpb  = (float*)alloc((size_t)B_ * N_ * H_ * 4);
    float* apb  = (float*)alloc((size_t)B_ * N_ * H_ * 4);
    float* E_vq = (float*)alloc((size_t)B_ * 2 * 9216 * 4);
    float* E_va = (float*)alloc((size_t)B_ * 2 * 9216 * 4);
    float* E_qa = (float*)alloc((size_t)B_ * 2 * 9216 * 4);
    float* Zinv = (float*)alloc(256);
    // total ~6.8 MB

    hipMemsetAsync(E_qa, 0, (size_t)B_ * 2 * 9216 * 4, stream);
    k_proj<<<288, 256, 0, stream>>>(v, q, a, Wvt, bvt, Wqt, bqt, Wat, bat,
                                    Wvp, bvp, Wqp, bqp, Wap, bap,
                                    vt, qt, at, vpb, qpb, apb);
    k_logits<<<512, 256, 0, stream>>>(vt, qt, at, Wg, E_vq, E_va, E_qa);
    k_zsum<<<32, 256, 0, stream>>>(E_vq, Zinv);
    k_ctx<<<576, 256, 0, stream>>>(E_vq, E_va, E_qa, vpb, qpb, apb, Zinv,
                                   (float*)d_out);
    k_update<<<576, 256, 0, stream>>>(v, q, a, Wvu, bvu, Wqu, bqu, Wau, bau,
                                      (float*)d_out);
}

// Round 7
// 215.650 us; speedup vs baseline: 1.3189x; 1.0404x over previous
//
#include <hip/hip_runtime.h>

// TriAttention factorized implementation — all-f32 I/O, bf16 MFMA logits.
// dims: B=16, N(v,q,a)=96, D=256, H=128, G=2
// l[v,q,a,g] = sum_h (qt[q,h]*Wg[h,g]) * (at[a,h]*vt[v,h]); contractions
// factor through pairwise marginals of softmax(l) (p never materialized).
// R6: k_logits E_qa via coalesced partial stores + reducer (no far atomics);
// k_proj restructured to grid 768, LDS=x-tile only, W from L2, no barriers.
// Workspace ~26 MB (E_qa_part 18.9 MB).

#define B_  16
#define N_  96
#define D_  256
#define H_  128
#define CV  6     // v rows per k_logits workgroup
#define NCH 16    // v-chunks = 96/CV
#define PAD 136   // LDS row stride in bf16 elems (272 B, 16B-aligned)

typedef short bf16x8_t __attribute__((ext_vector_type(8)));
typedef float f32x4_t  __attribute__((ext_vector_type(4)));

__device__ __forceinline__ float bf2f(unsigned short u) {
    union { unsigned u32; float f; } x;
    x.u32 = ((unsigned)u) << 16;
    return x.f;
}
__device__ __forceinline__ unsigned short f2bf(float f) {
    union { float f; unsigned u; } x;
    x.f = f;
    unsigned r = x.u + 0x7fffu + ((x.u >> 16) & 1u);   // RNE
    return (unsigned short)(r >> 16);
}

// ---------------------------------------------------------------------------
// Kernel 1 (R6): six projections x@W+b -> [B,96,128]; tucker (p<3) relu'd +
// bf16, value projections (p>=3) f32. grid = 6p*16b*8tc = 768 (3 WG/CU),
// 12 tokens/WG. LDS holds only the x-tile (12 KB); W streams from L2
// (6 x 128 KB, hot across 128 WGs each). No mid-kernel barriers.
// ---------------------------------------------------------------------------
__global__ __launch_bounds__(256) void k_proj(
    const float* __restrict__ v, const float* __restrict__ q,
    const float* __restrict__ a,
    const float* __restrict__ Wvt, const float* __restrict__ bvt,
    const float* __restrict__ Wqt, const float* __restrict__ bqt,
    const float* __restrict__ Wat, const float* __restrict__ bat,
    const float* __restrict__ Wvp, const float* __restrict__ bvp,
    const float* __restrict__ Wqp, const float* __restrict__ bqp,
    const float* __restrict__ Wap, const float* __restrict__ bap,
    unsigned short* __restrict__ vt_o, unsigned short* __restrict__ qt_o,
    unsigned short* __restrict__ at_o,
    float* __restrict__ vp_o, float* __restrict__ qp_o, float* __restrict__ ap_o)
{
    int wg = blockIdx.x;
    int tc = wg % 8, b = (wg / 8) & 15, p = wg / 128;
    const float* xs_[6] = {v, q, a, v, q, a};
    const float* Ws_[6] = {Wvt, Wqt, Wat, Wvp, Wqp, Wap};
    const float* bs_[6] = {bvt, bqt, bat, bvp, bqp, bap};

    __shared__ __align__(16) float x_l[12 * D_];   // 12 KB

    int tid = threadIdx.x;
    int t0 = tc * 12;
    const float* x = xs_[p] + (size_t)(b * N_ + t0) * D_;
    for (int i = tid; i < 768; i += 256)           // 3072 floats as float4
        ((float4*)x_l)[i] = ((const float4*)x)[i];
    __syncthreads();

    int d = tid & 127, tg = tid >> 7;              // 2 groups x 6 tokens
    const float* W = Ws_[p];
    float bias = bs_[p][d];
    float acc[6];
#pragma unroll
    for (int t = 0; t < 6; t++) acc[t] = bias;

    for (int kb = 0; kb < 32; kb++) {
        int k = kb * 8;
        float w0 = W[(k + 0) * H_ + d], w1 = W[(k + 1) * H_ + d];
        float w2 = W[(k + 2) * H_ + d], w3 = W[(k + 3) * H_ + d];
        float w4 = W[(k + 4) * H_ + d], w5 = W[(k + 5) * H_ + d];
        float w6 = W[(k + 6) * H_ + d], w7 = W[(k + 7) * H_ + d];
#pragma unroll
        for (int t = 0; t < 6; t++) {
            int lt = tg * 6 + t;
            float4 xa = *(const float4*)&x_l[lt * D_ + k];
            float4 xb = *(const float4*)&x_l[lt * D_ + k + 4];
            acc[t] += xa.x * w0 + xa.y * w1 + xa.z * w2 + xa.w * w3
                    + xb.x * w4 + xb.y * w5 + xb.z * w6 + xb.w * w7;
        }
    }

    int trow = b * N_ + t0 + tg * 6;
    if (p < 3) {
        unsigned short* outs[3] = {vt_o, qt_o, at_o};
        unsigned short* o = outs[p];
#pragma unroll
        for (int t = 0; t < 6; t++)
            o[(trow + t) * H_ + d] = f2bf(fmaxf(acc[t], 0.f));   // FCNet relu
    } else {
        float* outs[3] = {vp_o, qp_o, ap_o};
        float* o = outs[p - 3];
#pragma unroll
        for (int t = 0; t < 6; t++) o[(trow + t) * H_ + d] = acc[t];
    }
}

// ---------------------------------------------------------------------------
// Kernel 2 (R6): logits + exp + marginals. WG = (b, vc of CV=6, g), grid 512.
// qg = qt*Wg[:,g] staged once; as = at*vt[v] staged per v; 3x3 tile blocks
// per wave. E_vq/E_va via shuffles + LDS atomics. E_qa partials now stored
// PLAIN + COALESCED into E_qa_part[slot][idx][tid] (no device-scope atomics
// -> no far-atomic EA traffic); reduced in k_reduce.
// ---------------------------------------------------------------------------
__global__ __launch_bounds__(256) void k_logits(
    const unsigned short* __restrict__ vt, const unsigned short* __restrict__ qt,
    const unsigned short* __restrict__ at, const float* __restrict__ Wg,
    float* __restrict__ E_vq, float* __restrict__ E_va,
    float* __restrict__ E_qa_part)
{
    int bid = blockIdx.x;
    int b = bid >> 5, vc = (bid >> 1) & 15, g = bid & 1;
    int tid = threadIdx.x;

    __shared__ __align__(16) unsigned short qg_l[N_ * PAD];  // qt*Wg[:,g]
    __shared__ __align__(16) unsigned short as_l[N_ * PAD];  // at*vt[v]
    __shared__ float evq_l[N_];
    __shared__ float eva_l[N_];

    const unsigned short* qtb = qt + (size_t)b * N_ * H_;
    const unsigned short* atb = at + (size_t)b * N_ * H_;
    const unsigned short* vtb = vt + (size_t)(b * N_ + vc * CV) * H_;

    for (int it = 0; it < 12; it++) {
        int i = tid + it * 256;
        int e = i * 4, t = e >> 7, h = e & 127;
        ushort4 qv = *(const ushort4*)&qtb[e];
        float w0 = Wg[(h + 0) * 2 + g], w1 = Wg[(h + 1) * 2 + g];
        float w2 = Wg[(h + 2) * 2 + g], w3 = Wg[(h + 3) * 2 + g];
        ushort4 o;
        o.x = f2bf(bf2f(qv.x) * w0);
        o.y = f2bf(bf2f(qv.y) * w1);
        o.z = f2bf(bf2f(qv.z) * w2);
        o.w = f2bf(bf2f(qv.w) * w3);
        *(ushort4*)&qg_l[t * PAD + h] = o;
    }
    if (tid < 96) evq_l[tid] = 0.f;
    else if (tid < 192) eva_l[tid - 96] = 0.f;

    int wave = tid >> 6, lane = tid & 63, quad = lane >> 4, l15 = lane & 15;
    int qi0 = (wave >> 1) * 3, aj0 = (wave & 1) * 3;

    float eqa[3][3][4];
#pragma unroll
    for (int i = 0; i < 3; i++)
#pragma unroll
        for (int j = 0; j < 3; j++)
#pragma unroll
            for (int r = 0; r < 4; r++) eqa[i][j][r] = 0.f;

    for (int vl = 0; vl < CV; vl++) {
        __syncthreads();
        const unsigned short* vrow = vtb + vl * H_;
        for (int it = 0; it < 12; it++) {
            int i = tid + it * 256;
            int e = i * 4, t = e >> 7, h = e & 127;
            ushort4 av = *(const ushort4*)&atb[e];
            ushort4 vv = *(const ushort4*)&vrow[h];
            ushort4 o;
            o.x = f2bf(bf2f(av.x) * bf2f(vv.x));
            o.y = f2bf(bf2f(av.y) * bf2f(vv.y));
            o.z = f2bf(bf2f(av.z) * bf2f(vv.z));
            o.w = f2bf(bf2f(av.w) * bf2f(vv.w));
            *(ushort4*)&as_l[t * PAD + h] = o;
        }
        __syncthreads();

        f32x4_t acc[3][3];
#pragma unroll
        for (int i = 0; i < 3; i++)
#pragma unroll
            for (int j = 0; j < 3; j++)
                acc[i][j] = (f32x4_t){0.f, 0.f, 0.f, 0.f};
#pragma unroll
        for (int ks = 0; ks < 4; ks++) {
            bf16x8_t af[3], bfr[3];
#pragma unroll
            for (int i = 0; i < 3; i++)
                af[i] = *(const bf16x8_t*)&qg_l[((qi0 + i) * 16 + l15) * PAD + ks * 32 + quad * 8];
#pragma unroll
            for (int j = 0; j < 3; j++)
                bfr[j] = *(const bf16x8_t*)&as_l[((aj0 + j) * 16 + l15) * PAD + ks * 32 + quad * 8];
#pragma unroll
            for (int i = 0; i < 3; i++)
#pragma unroll
                for (int j = 0; j < 3; j++)
                    acc[i][j] = __builtin_amdgcn_mfma_f32_16x16x32_bf16(af[i], bfr[j], acc[i][j], 0, 0, 0);
        }

        // C/D: col(a)=l15, row(q)=quad*4+r  [m89-verified]
        float s[3][4];
        float c[3];
#pragma unroll
        for (int i = 0; i < 3; i++) {
            s[i][0] = 0.f; s[i][1] = 0.f; s[i][2] = 0.f; s[i][3] = 0.f;
        }
        c[0] = 0.f; c[1] = 0.f; c[2] = 0.f;
#pragma unroll
        for (int i = 0; i < 3; i++)
#pragma unroll
            for (int j = 0; j < 3; j++) {
                float e0 = __expf(fminf(fmaxf(acc[i][j][0], -30.f), 30.f));
                float e1 = __expf(fminf(fmaxf(acc[i][j][1], -30.f), 30.f));
                float e2 = __expf(fminf(fmaxf(acc[i][j][2], -30.f), 30.f));
                float e3 = __expf(fminf(fmaxf(acc[i][j][3], -30.f), 30.f));
                eqa[i][j][0] += e0; eqa[i][j][1] += e1;
                eqa[i][j][2] += e2; eqa[i][j][3] += e3;
                s[i][0] += e0; s[i][1] += e1; s[i][2] += e2; s[i][3] += e3;
                c[j] += e0 + e1 + e2 + e3;
            }
#pragma unroll
        for (int i = 0; i < 3; i++) {
            float s0 = s[i][0], s1 = s[i][1], s2 = s[i][2], s3 = s[i][3];
#pragma unroll
            for (int m = 1; m < 16; m <<= 1) {
                s0 += __shfl_xor(s0, m); s1 += __shfl_xor(s1, m);
                s2 += __shfl_xor(s2, m); s3 += __shfl_xor(s3, m);
            }
            if (l15 == 0) {
                int qr = (qi0 + i) * 16 + quad * 4;
                atomicAdd(&evq_l[qr + 0], s0);
                atomicAdd(&evq_l[qr + 1], s1);
                atomicAdd(&evq_l[qr + 2], s2);
                atomicAdd(&evq_l[qr + 3], s3);
            }
        }
#pragma unroll
        for (int j = 0; j < 3; j++) {
            float cs = c[j];
            cs += __shfl_xor(cs, 16);
            cs += __shfl_xor(cs, 32);
            if (lane < 16) atomicAdd(&eva_l[(aj0 + j) * 16 + l15], cs);
        }
        __syncthreads();
        int base = ((b * 2 + g) * N_ + vc * CV + vl) * N_;
        if (tid < 96)       { E_vq[base + tid] = evq_l[tid];       evq_l[tid] = 0.f; }
        else if (tid < 192) { E_va[base + tid - 96] = eva_l[tid - 96]; eva_l[tid - 96] = 0.f; }
    }

    // E_qa partial flush: plain coalesced stores, layout [slot][idx][tid]
    float* Pp = E_qa_part + (size_t)((b * NCH + vc) * 2 + g) * 9216;
#pragma unroll
    for (int i = 0; i < 3; i++)
#pragma unroll
        for (int j = 0; j < 3; j++)
#pragma unroll
            for (int r = 0; r < 4; r++) {
                int idx = (i * 3 + j) * 4 + r;
                Pp[idx * 256 + tid] = eqa[i][j][r];
            }
}

// ---------------------------------------------------------------------------
// Kernel 3 (R6): reduce E_qa partials over the 16 vc slots (inverting the
// [idx][tid] -> (qq,aa) mapping) and compute Zinv = 1/sum(E_vq). grid = 32.
// ---------------------------------------------------------------------------
__global__ __launch_bounds__(256) void k_reduce(
    const float* __restrict__ E_qa_part, const float* __restrict__ E_vq,
    float* __restrict__ E_qa, float* __restrict__ Zinv)
{
    int b = blockIdx.x >> 1, g = blockIdx.x & 1;
    int tid = threadIdx.x;
    int wave = tid >> 6, lane = tid & 63, quad = lane >> 4, l15 = lane & 15;
    int qi0 = (wave >> 1) * 3, aj0 = (wave & 1) * 3;
    float* Eq = E_qa + (size_t)(b * 2 + g) * 9216;

    for (int idx = 0; idx < 36; idx++) {
        float s = 0.f;
        const float* Pp = E_qa_part + (size_t)(b * NCH * 2 + g) * 9216 + idx * 256 + tid;
#pragma unroll
        for (int vc = 0; vc < NCH; vc++) s += Pp[(size_t)vc * 2 * 9216];
        int i = idx / 12, j = (idx / 4) % 3, r = idx & 3;
        int qq = (qi0 + i) * 16 + quad * 4 + r;
        int aa = (aj0 + j) * 16 + l15;
        Eq[qq * 96 + aa] = s;
    }

    float z = 0.f;
    const float* ev = E_vq + (b * 2 + g) * 9216;
    for (int i = tid; i < 9216; i += 256) z += ev[i];
    __shared__ float red[256];
    red[tid] = z;
    __syncthreads();
    for (int s2 = 128; s2 > 0; s2 >>= 1) {
        if (tid < s2) red[tid] += red[tid + s2];
        __syncthreads();
    }
    if (tid == 0) Zinv[b * 2 + g] = 1.f / fmaxf(red[0], 1e-30f);
}

// ---------------------------------------------------------------------------
// Kernel 4: attended contexts from marginals; c written f32 directly into
// d_out at final positions (c_v/c_q col=g*128+d, c_a col=d*2+g). grid = 576.
// ---------------------------------------------------------------------------
__global__ __launch_bounds__(256) void k_ctx(
    const float* __restrict__ E_vq, const float* __restrict__ E_va,
    const float* __restrict__ E_qa,
    const float* __restrict__ vp, const float* __restrict__ qp,
    const float* __restrict__ ap, const float* __restrict__ Zinv,
    float* __restrict__ out)
{
    int wg = blockIdx.x;
    int tc = wg % 6, g = (wg / 6) & 1, b = (wg / 12) & 15, o = wg / 192;
    int tid = threadIdx.x;
    __shared__ __align__(16) float E1l[16 * 100];
    __shared__ __align__(16) float E2l[16 * 100];
    int t0 = tc * 16;
    const float* Evq = E_vq + (b * 2 + g) * 9216;
    const float* Eva = E_va + (b * 2 + g) * 9216;
    const float* Eqa = E_qa + (b * 2 + g) * 9216;

    if (o == 0) {          // c_v: E1[t=v][j=q]=E_vq, E2[t=v][j=a]=E_va
        for (int i = tid; i < 1536; i += 256) {
            int t = i / 96, j = i - t * 96;
            E1l[t * 100 + j] = Evq[(t0 + t) * 96 + j];
            E2l[t * 100 + j] = Eva[(t0 + t) * 96 + j];
        }
    } else if (o == 1) {   // c_q: E1[t=q][j=v]=E_vq^T, E2[t=q][j=a]=E_qa
        for (int i = tid; i < 1536; i += 256) {
            int t = i & 15, j = i >> 4;
            E1l[t * 100 + j] = Evq[j * 96 + t0 + t];
        }
        for (int i = tid; i < 1536; i += 256) {
            int t = i / 96, j = i - t * 96;
            E2l[t * 100 + j] = Eqa[(t0 + t) * 96 + j];
        }
    } else {               // c_a: E1[t=a][j=v]=E_va^T, E2[t=a][j=q]=E_qa^T
        for (int i = tid; i < 1536; i += 256) {
            int t = i & 15, j = i >> 4;
            E1l[t * 100 + j] = Eva[j * 96 + t0 + t];
            E2l[t * 100 + j] = Eqa[j * 96 + t0 + t];
        }
    }
    __syncthreads();

    const float* P1 = ((o == 0) ? qp : vp) + b * N_ * H_;
    const float* P2 = ((o == 2) ? qp : ap) + b * N_ * H_;
    int d = tid & 127, tg = tid >> 7;
    float acc[8] = {0.f, 0.f, 0.f, 0.f, 0.f, 0.f, 0.f, 0.f};
    for (int jb = 0; jb < 24; jb++) {
        int j4 = jb * 4;
        float p10 = P1[(j4 + 0) * H_ + d], p11 = P1[(j4 + 1) * H_ + d];
        float p12 = P1[(j4 + 2) * H_ + d], p13 = P1[(j4 + 3) * H_ + d];
        float p20 = P2[(j4 + 0) * H_ + d], p21 = P2[(j4 + 1) * H_ + d];
        float p22 = P2[(j4 + 2) * H_ + d], p23 = P2[(j4 + 3) * H_ + d];
#pragma unroll
        for (int t8 = 0; t8 < 8; t8++) {
            int t = tg * 8 + t8;
            float4 e1 = *(const float4*)&E1l[t * 100 + j4];
            float4 e2 = *(const float4*)&E2l[t * 100 + j4];
            acc[t8] += e1.x * p10 + e1.y * p11 + e1.z * p12 + e1.w * p13
                     + e2.x * p20 + e2.y * p21 + e2.z * p22 + e2.w * p23;
        }
    }
    float zi = Zinv[b * 2 + g];
    float* ob = out + (size_t)((o * B_ + b) * N_) * 256;
#pragma unroll
    for (int t8 = 0; t8 < 8; t8++) {
        int T = t0 + tg * 8 + t8;
        int col = (o == 2) ? (d * 2 + g) : (g * 128 + d);
        ob[T * 256 + col] = acc[t8] * zi;
    }
}

// ---------------------------------------------------------------------------
// Kernel 5: updated_x = x + c_x @ Wxu + bxu, in place over d_out. grid = 576.
// ---------------------------------------------------------------------------
__global__ __launch_bounds__(256) void k_update(
    const float* __restrict__ v, const float* __restrict__ q,
    const float* __restrict__ a,
    const float* __restrict__ Wvu, const float* __restrict__ bvu,
    const float* __restrict__ Wqu, const float* __restrict__ bqu,
    const float* __restrict__ Wau, const float* __restrict__ bau,
    float* __restrict__ out)
{
    int wg = blockIdx.x;
    int tc = wg % 12, b = (wg / 12) & 15, o = wg / 192;
    int tid = threadIdx.x;
    const float* xs_[3] = {v, q, a};
    const float* Ws_[3] = {Wvu, Wqu, Wau};
    const float* bs_[3] = {bvu, bqu, bau};
    int t0 = tc * 8;

    __shared__ __align__(16) float c_l[8 * 256];
    float* cbase = out + (size_t)((o * B_ + b) * N_ + t0) * 256;
    for (int i = tid; i < 2048; i += 256) c_l[i] = cbase[i];
    __syncthreads();

    const float* W = Ws_[o];
    const float* x = xs_[o] + (size_t)(b * N_ + t0) * 256;
    float bias = bs_[o][tid];
    float acc[8];
#pragma unroll
    for (int t = 0; t < 8; t++) acc[t] = bias + x[t * 256 + tid];

    for (int kb = 0; kb < 64; kb++) {
        int k = kb * 4;
        float w0 = W[(k + 0) * 256 + tid];
        float w1 = W[(k + 1) * 256 + tid];
        float w2 = W[(k + 2) * 256 + tid];
        float w3 = W[(k + 3) * 256 + tid];
#pragma unroll
        for (int t = 0; t < 8; t++) {
            float4 c4 = *(const float4*)&c_l[t * 256 + k];
            acc[t] += c4.x * w0 + c4.y * w1 + c4.z * w2 + c4.w * w3;
        }
    }
#pragma unroll
    for (int t = 0; t < 8; t++) cbase[t * 256 + tid] = acc[t];
}

// ---------------------------------------------------------------------------
extern "C" void kernel_launch(void* const* d_in, const int* in_sizes, int n_in,
                              void* d_out, int out_size, void* d_ws, size_t ws_size,
                              hipStream_t stream)
{
    const float* v   = (const float*)d_in[0];
    const float* q   = (const float*)d_in[1];
    const float* a   = (const float*)d_in[2];
    const float* Wvt = (const float*)d_in[3];
    const float* bvt = (const float*)d_in[4];
    const float* Wqt = (const float*)d_in[5];
    const float* bqt = (const float*)d_in[6];
    const float* Wat = (const float*)d_in[7];
    const float* bat = (const float*)d_in[8];
    const float* Wg  = (const float*)d_in[9];
    const float* Wvp = (const float*)d_in[10];
    const float* bvp = (const float*)d_in[11];
    const float* Wqp = (const float*)d_in[12];
    const float* bqp = (const float*)d_in[13];
    const float* Wap = (const float*)d_in[14];
    const float* bap = (const float*)d_in[15];
    const float* Wvu = (const float*)d_in[16];
    const float* bvu = (const float*)d_in[17];
    const float* Wqu = (const float*)d_in[18];
    const float* bqu = (const float*)d_in[19];
    const float* Wau = (const float*)d_in[20];
    const float* bau = (const float*)d_in[21];

    char* ws = (char*)d_ws;
    size_t off = 0;
    auto alloc = [&](size_t bytes) {
        char* p = ws + off;
        off += (bytes + 255) & ~(size_t)255;
        return (void*)p;
    };
    unsigned short* vt = (unsigned short*)alloc((size_t)B_ * N_ * H_ * 2);
    unsigned short* qt = (unsigned short*)alloc((size_t)B_ * N_ * H_ * 2);
    unsigned short* at = (unsigned short*)alloc((size_t)B_ * N_ * H_ * 2);
    float* vpb  = (float*)alloc((size_t)B_ * N_ * H_ * 4);
    float* qpb  = (float*)alloc((size_t)B_ * N_ * H_ * 4);
    float* apb  = (float*)alloc((size_t)B_ * N_ * H_ * 4);
    float* E_vq = (float*)alloc((size_t)B_ * 2 * 9216 * 4);
    float* E_va = (float*)alloc((size_t)B_ * 2 * 9216 * 4);
    float* E_qa = (float*)alloc((size_t)B_ * 2 * 9216 * 4);
    float* Zinv = (float*)alloc(256);
    float* E_qa_part = (float*)alloc((size_t)B_ * NCH * 2 * 9216 * 4);  // 18.9 MB
    // total ~26 MB

    k_proj<<<768, 256, 0, stream>>>(v, q, a, Wvt, bvt, Wqt, bqt, Wat, bat,
                                    Wvp, bvp, Wqp, bqp, Wap, bap,
                                    vt, qt, at, vpb, qpb, apb);
    k_logits<<<512, 256, 0, stream>>>(vt, qt, at, Wg, E_vq, E_va, E_qa_part);
    k_reduce<<<32, 256, 0, stream>>>(E_qa_part, E_vq, E_qa, Zinv);
    k_ctx<<<576, 256, 0, stream>>>(E_vq, E_va, E_qa, vpb, qpb, apb, Zinv,
                                   (float*)d_out);
    k_update<<<576, 256, 0, stream>>>(v, q, a, Wvu, bvu, Wqu, bqu, Wau, bau,
                                      (float*)d_out);
}